// Round 3
// baseline (254.065 us; speedup 1.0000x reference)
//
#include <hip/hip_runtime.h>
#include <stdint.h>

#define TT 2048
#define DD 1024
#define HH 16
#define LDP 4368   // concat width: 3072 qkv | 64 w1 | 64 w2 | 64 r1 | 64 r2 | 1024 memv | 16 gate

using bf16x8 = __attribute__((ext_vector_type(8))) __bf16;
using f32x4  = __attribute__((ext_vector_type(4))) float;

__device__ __forceinline__ float bf2f(unsigned short u){
  unsigned int x = ((unsigned int)u) << 16;
  return __builtin_bit_cast(float, x);
}
__device__ __forceinline__ unsigned short f2bf(float f){
  unsigned int x = __builtin_bit_cast(unsigned int, f);
  x += 0x7fffu + ((x >> 16) & 1u);
  return (unsigned short)(x >> 16);
}
__device__ __forceinline__ float sigmoidf_(float x){ return 1.0f/(1.0f+__expf(-x)); }

// global -> LDS direct (16B/lane). LDS base must be wave-uniform; HW adds lane*16.
__device__ __forceinline__ void gload_lds16(const void* g, void* l){
  auto gp = (const __attribute__((address_space(1))) unsigned int*)(uintptr_t)g;
  auto lp = (__attribute__((address_space(3))) unsigned int*)(unsigned int)(uintptr_t)l;
  __builtin_amdgcn_global_load_lds(gp, lp, 16, 0, 0);
}

// ---------------- weight prep ----------------
__global__ void prep_weights_kernel(const float* __restrict__ qkv_w, const float* __restrict__ w1w,
                                    const float* __restrict__ w2w, const float* __restrict__ r1w,
                                    const float* __restrict__ r2w, const float* __restrict__ memv_w,
                                    const float* __restrict__ memg_w, const float* __restrict__ out_w,
                                    const float* __restrict__ qkv_b, const float* __restrict__ memv_b,
                                    const float* __restrict__ memg_b,
                                    unsigned short* __restrict__ Wcat, float* __restrict__ bcat)
{
  const int idx = blockIdx.x*256 + threadIdx.x;     // 5392*256 exact
  {
    const int row = idx >> 8, c4 = (idx & 255)*4;
    const float* src; int r;
    if      (row < 3072) { src = qkv_w;  r = row; }
    else if (row < 3136) { src = w1w;    r = row-3072; }
    else if (row < 3200) { src = w2w;    r = row-3136; }
    else if (row < 3264) { src = r1w;    r = row-3200; }
    else if (row < 3328) { src = r2w;    r = row-3264; }
    else if (row < 4352) { src = memv_w; r = row-3328; }
    else if (row < 4368) { src = memg_w; r = row-4352; }
    else                 { src = out_w;  r = row-4368; }
    const float4 v = *(const float4*)(src + (size_t)r*1024 + c4);
    ushort4 o; o.x=f2bf(v.x); o.y=f2bf(v.y); o.z=f2bf(v.z); o.w=f2bf(v.w);
    *(ushort4*)(Wcat + (size_t)row*1024 + c4) = o;
  }
  if (idx < 4368) {
    float v;
    if      (idx < 3072) v = qkv_b[idx];
    else if (idx < 3328) v = 0.f;
    else if (idx < 4352) v = memv_b[idx-3328];
    else                 v = memg_b[idx-4352];
    bcat[idx] = v;
  }
}

__global__ void convert_x_kernel(const float* __restrict__ x, unsigned short* __restrict__ xb)
{
  const int idx = blockIdx.x*256 + threadIdx.x;   // 4096*256 exact, 4 elems each
  const float4 v = ((const float4*)x)[idx];
  ushort4 o; o.x=f2bf(v.x); o.y=f2bf(v.y); o.z=f2bf(v.z); o.w=f2bf(v.w);
  ((ushort4*)xb)[idx] = o;
}

// ---------------- GEMM: C[M,N] = A[M,K] * Bt[N,K]^T + bias ----------------
template<bool OUTF32>
__global__ __launch_bounds__(256, 2)
void gemm_bt_kernel(const unsigned short* __restrict__ A, int lda,
                    const unsigned short* __restrict__ Bt, int ldb,
                    const float* __restrict__ bias,
                    void* __restrict__ Cout, int ldc, int N, int K)
{
  __shared__ unsigned short As[128*32];
  __shared__ unsigned short Bs[128*32];
  const int tid = threadIdx.x;
  const int w = tid >> 6, lane = tid & 63;
  const int l15 = lane & 15, l4 = lane >> 4;
  const int m0 = blockIdx.x * 128;
  const int n0 = blockIdx.y * 128;
  const int wr = (w >> 1) * 64, wc = (w & 1) * 64;

  const f32x4 zero = {0.f,0.f,0.f,0.f};
  f32x4 acc[4][4];
#pragma unroll
  for (int i = 0; i < 4; ++i)
#pragma unroll
    for (int j = 0; j < 4; ++j) acc[i][j] = zero;

  const int srow = lane >> 2;
  const int k8   = (lane & 3) * 8;

  for (int k0 = 0; k0 < K; k0 += 32) {
    __syncthreads();
#pragma unroll
    for (int q = 0; q < 4; ++q) {
      const int c = q*4 + w;                 // 0..15 chunk of 1KB
      const int rloc = (c & 7)*16 + srow;
      if (c < 8) {
        gload_lds16(A + (size_t)(m0 + rloc)*lda + k0 + k8, (char*)As + (c&7)*1024);
      } else {
        int nrow = n0 + rloc; if (nrow >= N) nrow = N - 1;
        gload_lds16(Bt + (size_t)nrow*ldb + k0 + k8, (char*)Bs + (c&7)*1024);
      }
    }
    __syncthreads();
    bf16x8 af[4], bfr[4];
#pragma unroll
    for (int i = 0; i < 4; ++i) {
      af[i]  = *reinterpret_cast<const bf16x8*>(&As[(wr + i*16 + l15)*32 + l4*8]);
      bfr[i] = *reinterpret_cast<const bf16x8*>(&Bs[(wc + i*16 + l15)*32 + l4*8]);
    }
#pragma unroll
    for (int i = 0; i < 4; ++i)
#pragma unroll
      for (int j = 0; j < 4; ++j)
        acc[i][j] = __builtin_amdgcn_mfma_f32_16x16x32_bf16(af[i], bfr[j], acc[i][j], 0, 0, 0);
  }

#pragma unroll
  for (int i = 0; i < 4; ++i) {
    const int rowb = m0 + wr + i*16 + l4*4;
#pragma unroll
    for (int j = 0; j < 4; ++j) {
      const int col = n0 + wc + j*16 + l15;
      if (col < N) {
        const float bv = bias ? bias[col] : 0.0f;
#pragma unroll
        for (int r = 0; r < 4; ++r) {
          const float v = acc[i][j][r] + bv;
          const size_t off = (size_t)(rowb + r)*ldc + col;
          if (OUTF32) ((float*)Cout)[off] = v;
          else        ((unsigned short*)Cout)[off] = f2bf(v);
        }
      }
    }
  }
}

// ---------------- V transpose: P v-cols -> VT[b][h][d][t] ----------------
__global__ __launch_bounds__(256, 4)
void transpose_v_kernel(const unsigned short* __restrict__ P, unsigned short* __restrict__ VT)
{
  __shared__ unsigned short tile[64][66];
  const int t0 = blockIdx.x*64, h = blockIdx.y, b = blockIdx.z;
  for (int i = threadIdx.x; i < 4096; i += 256) {
    const int r = i >> 6, c = i & 63;
    tile[r][c] = P[(size_t)(b*TT + t0 + r)*LDP + 2048 + h*64 + c];
  }
  __syncthreads();
  for (int i = threadIdx.x; i < 4096; i += 256) {
    const int d = i >> 6, tl = i & 63;
    VT[(size_t)((b*HH + h)*64 + d)*TT + t0 + tl] = tile[tl][d];
  }
}

// ---------------- flash attention ----------------
// 1024 blocks, one 64-row q-tile each, 4 resident blocks/CU (LDS 40KB*4 = 160KB).
// Decode keeps each (b,h) group's 32 blocks on one XCD (KV L2 locality),
// big-qt-first with per-group rotation stagger for per-CU balance.
__global__ __launch_bounds__(256, 4)
void attn_kernel(const unsigned short* __restrict__ P,
                 const unsigned short* __restrict__ VT,
                 float* __restrict__ seqo)
{
  __shared__ unsigned short Ks[2][64*64];  // [k-row][64 d], rows XOR-swizzled
  __shared__ unsigned short Vs[2][64*64];  // [d-row][64 k], rows XOR-swizzled
  __shared__ unsigned short Pls[4*16*64];  // per-wave 16x64, XOR-swizzled

  const int tid = threadIdx.x;
  const int w = tid >> 6, lane = tid & 63;
  const int l15 = lane & 15, l4 = lane >> 4;

  // decode: n -> (qt, h, b) with XCD grouping + stagger
  const int n = blockIdx.x;
  const int xcd = n & 7, slot = n >> 3;
  const int grp = slot >> 5, i5 = slot & 31;
  const int qt = 31 - ((i5 + 8*grp) & 31);
  const int g = grp*8 + xcd;
  const int h = g & 15, b = g >> 4;
  const int qbase = qt * 64;

  auto stage = [&](int kt, int bufsel) {
#pragma unroll
    for (int q2 = 0; q2 < 2; ++q2) {
      const int idx = q2*256 + tid;
      const int r = idx >> 3;
      const int cb = ((idx & 7)*16) ^ ((r & 7) << 4);   // swizzled source column byte
      gload_lds16(P + (size_t)(b*TT + kt*64 + r)*LDP + 1024 + h*64 + (cb >> 1),
                  (char*)Ks[bufsel] + q2*4096 + w*1024);
      gload_lds16(VT + (size_t)((b*HH + h)*64 + r)*TT + kt*64 + (cb >> 1),
                  (char*)Vs[bufsel] + q2*4096 + w*1024);
    }
  };

  const f32x4 zero = {0.f,0.f,0.f,0.f};

  bf16x8 qa[2];
  {
    const size_t base = (size_t)(b*TT + qbase + w*16 + l15)*LDP + h*64 + l4*8;
    qa[0] = *reinterpret_cast<const bf16x8*>(P + base);
    qa[1] = *reinterpret_cast<const bf16x8*>(P + base + 32);
  }

  f32x4 o[4];
#pragma unroll
  for (int d = 0; d < 4; ++d) o[d] = zero;
  float mrow[4] = {-1e30f,-1e30f,-1e30f,-1e30f};
  float lrow[4] = {0.f,0.f,0.f,0.f};

  stage(0, 0);
  asm volatile("s_waitcnt vmcnt(0)" ::: "memory");
  __builtin_amdgcn_s_barrier();

  for (int kt = 0; kt <= qt; ++kt) {
    const int cur = kt & 1;
    if (kt < qt) stage(kt + 1, cur ^ 1);   // loads fly under this iteration's compute

    // ---- QK^T ----
    f32x4 s[4];
    __builtin_amdgcn_s_setprio(1);
#pragma unroll
    for (int nn = 0; nn < 4; ++nn) {
      f32x4 a = zero;
#pragma unroll
      for (int c = 0; c < 2; ++c) {
        const unsigned kbyte = (unsigned)((nn*16 + l15)*128)
                             + (((unsigned)(c*64 + l4*16)) ^ (((unsigned)l15 & 7u) << 4));
        const bf16x8 kb = *reinterpret_cast<const bf16x8*>((const char*)Ks[cur] + kbyte);
        a = __builtin_amdgcn_mfma_f32_16x16x32_bf16(qa[c], kb, a, 0, 0, 0);
      }
      s[nn] = a;
    }
    __builtin_amdgcn_s_setprio(0);

    if (kt == qt) {
#pragma unroll
      for (int nn = 0; nn < 4; ++nn)
#pragma unroll
        for (int j = 0; j < 4; ++j) {
          const int qrow = qbase + w*16 + l4*4 + j;
          const int kcol = kt*64 + nn*16 + l15;
          s[nn][j] = (kcol <= qrow) ? s[nn][j]*0.125f : -1e30f;
        }
    } else {
#pragma unroll
      for (int nn = 0; nn < 4; ++nn)
#pragma unroll
        for (int j = 0; j < 4; ++j) s[nn][j] *= 0.125f;
    }

    // ---- online softmax (rows live across l15 lanes) ----
    float corr[4];
#pragma unroll
    for (int j = 0; j < 4; ++j) {
      float v = fmaxf(fmaxf(s[0][j], s[1][j]), fmaxf(s[2][j], s[3][j]));
      v = fmaxf(v, __shfl_xor(v, 1));
      v = fmaxf(v, __shfl_xor(v, 2));
      v = fmaxf(v, __shfl_xor(v, 4));
      v = fmaxf(v, __shfl_xor(v, 8));
      const float mn = fmaxf(mrow[j], v);
      corr[j] = __expf(mrow[j] - mn);
      mrow[j] = mn;
      float sum = 0.f;
#pragma unroll
      for (int nn = 0; nn < 4; ++nn) {
        const float p = __expf(s[nn][j] - mn);
        s[nn][j] = p;
        sum += p;
      }
      sum += __shfl_xor(sum, 1);
      sum += __shfl_xor(sum, 2);
      sum += __shfl_xor(sum, 4);
      sum += __shfl_xor(sum, 8);
      lrow[j] = lrow[j]*corr[j] + sum;
    }

#pragma unroll
    for (int d = 0; d < 4; ++d)
#pragma unroll
      for (int j = 0; j < 4; ++j) o[d][j] *= corr[j];

    // ---- P -> per-wave LDS (bf16), row-major [16 q][64 k], byte ^= ((row&7)<<4) ----
    const unsigned pbase = (unsigned)(w*2048);
#pragma unroll
    for (int nn = 0; nn < 4; ++nn)
#pragma unroll
      for (int j = 0; j < 4; ++j) {
        const unsigned r = (unsigned)(l4*4 + j);
        unsigned byte = r*128u + (unsigned)(nn*16 + l15)*2u;
        byte ^= ((r & 7u) << 4);
        *(unsigned short*)((char*)Pls + pbase + byte) = f2bf(s[nn][j]);
      }
    // same-wave cross-lane LDS handoff: order + completion, no workgroup barrier
    asm volatile("s_waitcnt lgkmcnt(0)" ::: "memory");

    // ---- PV ----
    __builtin_amdgcn_s_setprio(1);
#pragma unroll
    for (int c = 0; c < 2; ++c) {
      unsigned abyte = (unsigned)(l15*128 + c*64 + l4*16);
      abyte ^= (((unsigned)l15 & 7u) << 4);
      const bf16x8 pa = *reinterpret_cast<const bf16x8*>((char*)Pls + pbase + abyte);
#pragma unroll
      for (int d = 0; d < 4; ++d) {
        const unsigned vbyte = (unsigned)((d*16 + l15)*128)
                             + (((unsigned)(c*64 + l4*16)) ^ (((unsigned)l15 & 7u) << 4));
        const bf16x8 vb = *reinterpret_cast<const bf16x8*>((const char*)Vs[cur] + vbyte);
        o[d] = __builtin_amdgcn_mfma_f32_16x16x32_bf16(pa, vb, o[d], 0, 0, 0);
      }
    }
    __builtin_amdgcn_s_setprio(0);

    // drain this wave's LDS reads, then next-tile staging loads; one barrier per tile
    asm volatile("s_waitcnt lgkmcnt(0)" ::: "memory");
    asm volatile("s_waitcnt vmcnt(0)" ::: "memory");
    __builtin_amdgcn_s_barrier();
  }

#pragma unroll
  for (int d = 0; d < 4; ++d)
#pragma unroll
    for (int j = 0; j < 4; ++j) {
      const int row = qbase + w*16 + l4*4 + j;
      seqo[(size_t)(b*TT + row)*DD + h*64 + d*16 + l15] = o[d][j] / lrow[j];
    }
}

// ---------------- exterior products + J6 map ----------------
__device__ __forceinline__ void ext6(const float* p, const float* q, float* L){
  L[0] = p[0]*q[1] - p[1]*q[0];
  L[1] = p[0]*q[2] - p[2]*q[0];
  L[2] = p[0]*q[3] - p[3]*q[0];
  L[3] = p[1]*q[2] - p[2]*q[1];
  L[4] = p[1]*q[3] - p[3]*q[1];
  L[5] = p[2]*q[3] - p[3]*q[2];
  const float n2 = L[0]*L[0]+L[1]*L[1]+L[2]*L[2]+L[3]*L[3]+L[4]*L[4]+L[5]*L[5];
  const float inv = 1.0f / fmaxf(sqrtf(n2), 1e-12f);
#pragma unroll
  for (int i = 0; i < 6; ++i) L[i] *= inv;
}

__global__ void exterior_kernel(const unsigned short* __restrict__ P,
                                float* __restrict__ Jw6, float* __restrict__ rd6)
{
  const int gid = blockIdx.x*256 + threadIdx.x;        // 65536 exact
  const int h = gid & 15, t = (gid >> 4) & (TT-1), b = gid >> 15;
  const size_t row = (size_t)(b*TT + t)*LDP;
  float w1[4], w2[4], r1[4], r2[4];
  if (t > 0) {
    const size_t rp = row - LDP;
#pragma unroll
    for (int j = 0; j < 4; ++j) w1[j] = bf2f(P[rp + 3072 + h*4 + j]);
  } else {
#pragma unroll
    for (int j = 0; j < 4; ++j) w1[j] = 0.f;
  }
#pragma unroll
  for (int j = 0; j < 4; ++j) {
    w2[j] = bf2f(P[row + 3136 + h*4 + j]);
    r1[j] = bf2f(P[row + 3200 + h*4 + j]);
    r2[j] = bf2f(P[row + 3264 + h*4 + j]);
  }
  float wl[6], rl[6];
  ext6(w1, w2, wl);
  ext6(r1, r2, rl);
  const float jw[6] = {wl[5], -wl[4], wl[3], wl[2], -wl[1], wl[0]};
  const size_t base = ((size_t)(b*HH + h)*TT + t)*6;
#pragma unroll
  for (int i = 0; i < 6; ++i) { Jw6[base+i] = jw[i]; rd6[base+i] = rl[i]; }
}

// ---------------- chunked scan: M[t+1] = d*(M[t] + Jw[t] (x) Jw[t]) ----------------
__global__ __launch_bounds__(64, 8)
void scan_passA(const float* __restrict__ Jw6, const float* __restrict__ decay_logits,
                float* __restrict__ E)
{
  const int bid = blockIdx.x;            // 512 = 32 seq * 16 chunks
  const int s = bid >> 4, c = bid & 15;
  const int lane = threadIdx.x;
  const int i = lane & 7, j = lane >> 3;
  const int ic = i < 6 ? i : 0, jc = j < 6 ? j : 0;
  const float d = sigmoidf_(decay_logits[s & (HH-1)]);
  const size_t base = ((size_t)s*TT + c*128)*6;
  float e = 0.f;
  for (int t = 0; t < 128; ++t) {
    const float ai = Jw6[base + t*6 + ic];
    const float aj = Jw6[base + t*6 + jc];
    e = d*(e + ai*aj);
  }
  if (i < 6 && j < 6) E[(size_t)bid*36 + j*6 + i] = e;
}

__global__ __launch_bounds__(64, 8)
void scan_passB(const float* __restrict__ E, const float* __restrict__ decay_logits,
                float* __restrict__ BC)
{
  const int s = blockIdx.x;              // 32
  const int lane = threadIdx.x;
  if (lane >= 36) return;
  const float d = sigmoidf_(decay_logits[s & (HH-1)]);
  const float dL = __powf(d, 128.0f);
  float bc = 0.f;
  for (int c = 0; c < 16; ++c) {
    BC[((size_t)s*16 + c)*36 + lane] = bc;
    bc = dL*bc + E[((size_t)s*16 + c)*36 + lane];
  }
}

__global__ __launch_bounds__(64, 8)
void scan_passC(const float* __restrict__ Jw6, const float* __restrict__ rd6,
                const float* __restrict__ BC, const float* __restrict__ decay_logits,
                const float* __restrict__ iter_mix, float* __restrict__ msc)
{
  const int bid = blockIdx.x;
  const int s = bid >> 4, c = bid & 15;
  const int h = s & (HH-1), bb = s >> 4;
  const int lane = threadIdx.x;
  const int i = lane & 7, j = lane >> 3;
  const bool valid = (i < 6) && (j < 6);
  const int ic = i < 6 ? i : 0, jc = j < 6 ? j : 0;
  const float d = sigmoidf_(decay_logits[h]);
  const float alpha = sigmoidf_(iter_mix[0]);
  float m = 0.f;
  if (valid) m = BC[((size_t)s*16 + c)*36 + j*6 + i];
  const size_t base = ((size_t)s*TT + c*128)*6;
  for (int t = 0; t < 128; ++t) {
    const float ai = Jw6[base + t*6 + ic];
    const float aj = Jw6[base + t*6 + jc];
    const float ri = rd6[base + t*6 + ic];
    const float rj = rd6[base + t*6 + jc];
    float part = valid ? ri*m : 0.f;            // y_j = sum_i r_i * M_ij
    part += __shfl_xor(part, 1);
    part += __shfl_xor(part, 2);
    part += __shfl_xor(part, 4);
    float contrib = (i == 0 && j < 6) ? part*((1.f-alpha)*rj + alpha*part) : 0.f;
    contrib += __shfl_xor(contrib, 8);
    contrib += __shfl_xor(contrib, 16);
    contrib += __shfl_xor(contrib, 32);
    if (lane == 0) msc[((size_t)bb*TT + c*128 + t)*HH + h] = contrib;
    m = d*(m + ai*aj);
  }
}

// ---------------- gate + mix -> z (bf16) ----------------
__global__ __launch_bounds__(256, 4)
void combine_kernel(const float* __restrict__ seqo, const unsigned short* __restrict__ P,
                    const float* __restrict__ msc, const float* __restrict__ mem_scale,
                    unsigned short* __restrict__ zb)
{
  const int w = threadIdx.x >> 6, lane = threadIdx.x & 63;
  const int row = blockIdx.x*4 + w;
  float val = 0.f;
  if (lane < HH) {
    const float ms = msc[(size_t)row*HH + lane];
    const float gl = bf2f(P[(size_t)row*LDP + 4352 + lane]);
    val = sigmoidf_(ms*mem_scale[lane]) * sigmoidf_(gl);
  }
  val += __shfl_xor(val, 1);
  val += __shfl_xor(val, 2);
  val += __shfl_xor(val, 4);
  val += __shfl_xor(val, 8);
  const float g = __shfl(val, 0) * (1.0f/16.0f);
  for (int it = 0; it < 16; ++it) {
    const int dcol = it*64 + lane;
    const float z = seqo[(size_t)row*DD + dcol] + g*bf2f(P[(size_t)row*LDP + 3328 + dcol]);
    zb[(size_t)row*DD + dcol] = f2bf(z);
  }
}

// ---------------- launch ----------------
extern "C" void kernel_launch(void* const* d_in, const int* in_sizes, int n_in,
                              void* d_out, int out_size, void* d_ws, size_t ws_size,
                              hipStream_t stream)
{
  const float* x            = (const float*)d_in[0];
  const float* qkv_w        = (const float*)d_in[1];
  const float* qkv_b        = (const float*)d_in[2];
  const float* w1w          = (const float*)d_in[3];
  const float* w2w          = (const float*)d_in[4];
  const float* r1w          = (const float*)d_in[5];
  const float* r2w          = (const float*)d_in[6];
  const float* memv_w       = (const float*)d_in[7];
  const float* memv_b       = (const float*)d_in[8];
  const float* memg_w       = (const float*)d_in[9];
  const float* memg_b       = (const float*)d_in[10];
  const float* mem_scale    = (const float*)d_in[11];
  const float* iter_mix     = (const float*)d_in[12];
  const float* out_w        = (const float*)d_in[13];
  const float* out_b        = (const float*)d_in[14];
  const float* decay_logits = (const float*)d_in[15];

  char* ws = (char*)d_ws;
  unsigned short* xb   = (unsigned short*)(ws + 0);          //  8,388,608 B
  unsigned short* Wcat = (unsigned short*)(ws + 8388608);    // 11,042,816 B
  float*          bcat = (float*)         (ws + 19431424);   //     17,472 B
  unsigned short* P    = (unsigned short*)(ws + 19449088);   // 35,782,656 B
  unsigned short* VT   = (unsigned short*)(ws + 55231744);   //  8,388,608 B
  float*          seqo = (float*)         (ws + 63620352);   // 16,777,216 B
  float*          Jw6  = (float*)         (ws + 80397568);   //  1,572,864 B
  float*          rd6  = (float*)         (ws + 81970432);   //  1,572,864 B
  float*          E    = (float*)         (ws + 83543296);   //     73,728 B
  float*          BC   = (float*)         (ws + 83617024);   //     73,728 B
  float*          msc  = (float*)         (ws + 83690752);   //    262,144 B
  unsigned short* zb   = xb;  // xb dead after GEMM1; reuse for z

  prep_weights_kernel<<<5392, 256, 0, stream>>>(qkv_w, w1w, w2w, r1w, r2w, memv_w, memg_w, out_w,
                                                qkv_b, memv_b, memg_b, Wcat, bcat);
  convert_x_kernel<<<4096, 256, 0, stream>>>(x, xb);
  gemm_bt_kernel<false><<<dim3(32, 35), 256, 0, stream>>>(xb, 1024, Wcat, 1024, bcat,
                                                          P, LDP, 4368, 1024);
  transpose_v_kernel<<<dim3(32, 16, 2), 256, 0, stream>>>(P, VT);
  attn_kernel<<<1024, 256, 0, stream>>>(P, VT, seqo);
  exterior_kernel<<<256, 256, 0, stream>>>(P, Jw6, rd6);
  scan_passA<<<512, 64, 0, stream>>>(Jw6, decay_logits, E);
  scan_passB<<<32, 64, 0, stream>>>(E, decay_logits, BC);
  scan_passC<<<512, 64, 0, stream>>>(Jw6, rd6, BC, decay_logits, iter_mix, msc);
  combine_kernel<<<1024, 256, 0, stream>>>(seqo, P, msc, mem_scale, zb);
  gemm_bt_kernel<true><<<dim3(32, 8), 256, 0, stream>>>(zb, 1024, Wcat + (size_t)4368*1024, 1024,
                                                        out_b, d_out, 1024, 1024, 1024);
}

// Round 4
// 244.967 us; speedup vs baseline: 1.0371x; 1.0371x over previous
//
#include <hip/hip_runtime.h>
#include <stdint.h>

#define TT 2048
#define DD 1024
#define HH 16
#define LDP 4368   // concat width: 3072 qkv | 64 w1 | 64 w2 | 64 r1 | 64 r2 | 1024 memv | 16 gate

using bf16x8 = __attribute__((ext_vector_type(8))) __bf16;
using f32x4  = __attribute__((ext_vector_type(4))) float;

__device__ __forceinline__ float bf2f(unsigned short u){
  unsigned int x = ((unsigned int)u) << 16;
  return __builtin_bit_cast(float, x);
}
__device__ __forceinline__ unsigned short f2bf(float f){
  unsigned int x = __builtin_bit_cast(unsigned int, f);
  x += 0x7fffu + ((x >> 16) & 1u);
  return (unsigned short)(x >> 16);
}
__device__ __forceinline__ float sigmoidf_(float x){ return 1.0f/(1.0f+__expf(-x)); }

// global -> LDS direct (16B/lane). LDS base must be wave-uniform; HW adds lane*16.
__device__ __forceinline__ void gload_lds16(const void* g, void* l){
  auto gp = (const __attribute__((address_space(1))) unsigned int*)(uintptr_t)g;
  auto lp = (__attribute__((address_space(3))) unsigned int*)(unsigned int)(uintptr_t)l;
  __builtin_amdgcn_global_load_lds(gp, lp, 16, 0, 0);
}

// ---------------- weight prep ----------------
__global__ void prep_weights_kernel(const float* __restrict__ qkv_w, const float* __restrict__ w1w,
                                    const float* __restrict__ w2w, const float* __restrict__ r1w,
                                    const float* __restrict__ r2w, const float* __restrict__ memv_w,
                                    const float* __restrict__ memg_w, const float* __restrict__ out_w,
                                    const float* __restrict__ qkv_b, const float* __restrict__ memv_b,
                                    const float* __restrict__ memg_b,
                                    unsigned short* __restrict__ Wcat, float* __restrict__ bcat)
{
  const int idx = blockIdx.x*256 + threadIdx.x;     // 5392*256 exact
  {
    const int row = idx >> 8, c4 = (idx & 255)*4;
    const float* src; int r;
    if      (row < 3072) { src = qkv_w;  r = row; }
    else if (row < 3136) { src = w1w;    r = row-3072; }
    else if (row < 3200) { src = w2w;    r = row-3136; }
    else if (row < 3264) { src = r1w;    r = row-3200; }
    else if (row < 3328) { src = r2w;    r = row-3264; }
    else if (row < 4352) { src = memv_w; r = row-3328; }
    else if (row < 4368) { src = memg_w; r = row-4352; }
    else                 { src = out_w;  r = row-4368; }
    const float4 v = *(const float4*)(src + (size_t)r*1024 + c4);
    ushort4 o; o.x=f2bf(v.x); o.y=f2bf(v.y); o.z=f2bf(v.z); o.w=f2bf(v.w);
    *(ushort4*)(Wcat + (size_t)row*1024 + c4) = o;
  }
  if (idx < 4368) {
    float v;
    if      (idx < 3072) v = qkv_b[idx];
    else if (idx < 3328) v = 0.f;
    else if (idx < 4352) v = memv_b[idx-3328];
    else                 v = memg_b[idx-4352];
    bcat[idx] = v;
  }
}

__global__ void convert_x_kernel(const float* __restrict__ x, unsigned short* __restrict__ xb)
{
  const int idx = blockIdx.x*256 + threadIdx.x;   // 4096*256 exact, 4 elems each
  const float4 v = ((const float4*)x)[idx];
  ushort4 o; o.x=f2bf(v.x); o.y=f2bf(v.y); o.z=f2bf(v.z); o.w=f2bf(v.w);
  ((ushort4*)xb)[idx] = o;
}

// ---------------- GEMM: C[M,N] = A[M,K] * Bt[N,K]^T + bias ----------------
// 2-phase pipeline: stage(next) issued before compute(cur); one vmcnt(0)+barrier per k-step.
template<bool OUTF32>
__global__ __launch_bounds__(256, 2)
void gemm_bt_kernel(const unsigned short* __restrict__ A, int lda,
                    const unsigned short* __restrict__ Bt, int ldb,
                    const float* __restrict__ bias,
                    void* __restrict__ Cout, int ldc, int N, int K)
{
  __shared__ unsigned short As[2][128*32];
  __shared__ unsigned short Bs[2][128*32];
  const int tid = threadIdx.x;
  const int w = tid >> 6, lane = tid & 63;
  const int l15 = lane & 15, l4 = lane >> 4;
  const int m0 = blockIdx.x * 128;
  const int n0 = blockIdx.y * 128;
  const int wr = (w >> 1) * 64, wc = (w & 1) * 64;

  const f32x4 zero = {0.f,0.f,0.f,0.f};
  f32x4 acc[4][4];
#pragma unroll
  for (int i = 0; i < 4; ++i)
#pragma unroll
    for (int j = 0; j < 4; ++j) acc[i][j] = zero;

  const int srow = lane >> 2;
  const int k8   = (lane & 3) * 8;

  auto stage = [&](int k0, int buf) {
#pragma unroll
    for (int q = 0; q < 4; ++q) {
      const int c = q*4 + w;                 // 0..15 chunk of 1KB
      const int rloc = (c & 7)*16 + srow;
      if (c < 8) {
        gload_lds16(A + (size_t)(m0 + rloc)*lda + k0 + k8, (char*)As[buf] + (c&7)*1024);
      } else {
        int nrow = n0 + rloc; if (nrow >= N) nrow = N - 1;
        gload_lds16(Bt + (size_t)nrow*ldb + k0 + k8, (char*)Bs[buf] + (c&7)*1024);
      }
    }
  };

  stage(0, 0);
  asm volatile("s_waitcnt vmcnt(0)" ::: "memory");
  __builtin_amdgcn_s_barrier();

  for (int k0 = 0; k0 < K; k0 += 32) {
    const int cur = (k0 >> 5) & 1;
    if (k0 + 32 < K) stage(k0 + 32, cur ^ 1);   // next-tile loads fly under compute

    bf16x8 af[4], bfr[4];
#pragma unroll
    for (int i = 0; i < 4; ++i) {
      af[i]  = *reinterpret_cast<const bf16x8*>(&As[cur][(wr + i*16 + l15)*32 + l4*8]);
      bfr[i] = *reinterpret_cast<const bf16x8*>(&Bs[cur][(wc + i*16 + l15)*32 + l4*8]);
    }
#pragma unroll
    for (int i = 0; i < 4; ++i)
#pragma unroll
      for (int j = 0; j < 4; ++j)
        acc[i][j] = __builtin_amdgcn_mfma_f32_16x16x32_bf16(af[i], bfr[j], acc[i][j], 0, 0, 0);

    asm volatile("s_waitcnt vmcnt(0)" ::: "memory");
    __builtin_amdgcn_s_barrier();
  }

#pragma unroll
  for (int i = 0; i < 4; ++i) {
    const int rowb = m0 + wr + i*16 + l4*4;
#pragma unroll
    for (int j = 0; j < 4; ++j) {
      const int col = n0 + wc + j*16 + l15;
      if (col < N) {
        const float bv = bias ? bias[col] : 0.0f;
#pragma unroll
        for (int r = 0; r < 4; ++r) {
          const float v = acc[i][j][r] + bv;
          const size_t off = (size_t)(rowb + r)*ldc + col;
          if (OUTF32) ((float*)Cout)[off] = v;
          else        ((unsigned short*)Cout)[off] = f2bf(v);
        }
      }
    }
  }
}

// ---------------- V transpose: P v-cols -> VT[b][h][d][t] ----------------
__global__ __launch_bounds__(256, 4)
void transpose_v_kernel(const unsigned short* __restrict__ P, unsigned short* __restrict__ VT)
{
  __shared__ unsigned short tile[64][66];
  const int t0 = blockIdx.x*64, h = blockIdx.y, b = blockIdx.z;
  for (int i = threadIdx.x; i < 4096; i += 256) {
    const int r = i >> 6, c = i & 63;
    tile[r][c] = P[(size_t)(b*TT + t0 + r)*LDP + 2048 + h*64 + c];
  }
  __syncthreads();
  for (int i = threadIdx.x; i < 4096; i += 256) {
    const int d = i >> 6, tl = i & 63;
    VT[(size_t)((b*HH + h)*64 + d)*TT + t0 + tl] = tile[tl][d];
  }
}

// ---------------- flash attention (paired q-tiles, 2-phase pipeline, swizzled LDS) ----------------
// 512 blocks, pairs {pi, 31-pi}: exactly 33 k-tile iterations per block (uniform).
// XCD-grouped decode: each (b,h) group's 16 pair-blocks pinned to one XCD (KV L2-resident).
__global__ __launch_bounds__(256, 2)
void attn_kernel(const unsigned short* __restrict__ P,
                 const unsigned short* __restrict__ VT,
                 float* __restrict__ seqo)
{
  __shared__ unsigned short Ks[2][64*64];  // [k-row][64 d], rows XOR-swizzled
  __shared__ unsigned short Vs[2][64*64];  // [d-row][64 k], rows XOR-swizzled
  __shared__ unsigned short Pls[4*16*64];  // per-wave 16x64, XOR-swizzled

  const int tid = threadIdx.x;
  const int w = tid >> 6, lane = tid & 63;
  const int l15 = lane & 15, l4 = lane >> 4;

  // decode: n -> (pi, h, b); groups of 4 (b,h) per XCD
  const int n = blockIdx.x;
  const int xcd = n & 7, slot = n >> 3;
  const int grp = slot >> 4, pi = slot & 15;
  const int g = grp*8 + xcd;
  const int h = g & 15, b = g >> 4;

  auto stage = [&](int kt, int bufsel) {
#pragma unroll
    for (int q2 = 0; q2 < 2; ++q2) {
      const int idx = q2*256 + tid;
      const int r = idx >> 3;
      const int cb = ((idx & 7)*16) ^ ((r & 7) << 4);   // swizzled source column byte
      gload_lds16(P + (size_t)(b*TT + kt*64 + r)*LDP + 1024 + h*64 + (cb >> 1),
                  (char*)Ks[bufsel] + q2*4096 + w*1024);
      gload_lds16(VT + (size_t)((b*HH + h)*64 + r)*TT + kt*64 + (cb >> 1),
                  (char*)Vs[bufsel] + q2*4096 + w*1024);
    }
  };

  const f32x4 zero = {0.f,0.f,0.f,0.f};

  for (int rep = 0; rep < 2; ++rep) {
    const int qt = rep == 0 ? pi : 31 - pi;
    const int qbase = qt * 64;

    bf16x8 qa[2];
    {
      const size_t base = (size_t)(b*TT + qbase + w*16 + l15)*LDP + h*64 + l4*8;
      qa[0] = *reinterpret_cast<const bf16x8*>(P + base);
      qa[1] = *reinterpret_cast<const bf16x8*>(P + base + 32);
    }

    f32x4 o[4];
#pragma unroll
    for (int d = 0; d < 4; ++d) o[d] = zero;
    float mrow[4] = {-1e30f,-1e30f,-1e30f,-1e30f};
    float lrow[4] = {0.f,0.f,0.f,0.f};

    stage(0, 0);
    asm volatile("s_waitcnt vmcnt(0)" ::: "memory");
    __builtin_amdgcn_s_barrier();

    for (int kt = 0; kt <= qt; ++kt) {
      const int cur = kt & 1;
      if (kt < qt) stage(kt + 1, cur ^ 1);   // loads fly under this iteration's compute

      // ---- QK^T ----
      f32x4 s[4];
#pragma unroll
      for (int nn = 0; nn < 4; ++nn) {
        f32x4 a = zero;
#pragma unroll
        for (int c = 0; c < 2; ++c) {
          const unsigned kbyte = (unsigned)((nn*16 + l15)*128)
                               + (((unsigned)(c*64 + l4*16)) ^ (((unsigned)l15 & 7u) << 4));
          const bf16x8 kb = *reinterpret_cast<const bf16x8*>((const char*)Ks[cur] + kbyte);
          a = __builtin_amdgcn_mfma_f32_16x16x32_bf16(qa[c], kb, a, 0, 0, 0);
        }
        s[nn] = a;
      }

      if (kt == qt) {
#pragma unroll
        for (int nn = 0; nn < 4; ++nn)
#pragma unroll
          for (int j = 0; j < 4; ++j) {
            const int qrow = qbase + w*16 + l4*4 + j;
            const int kcol = kt*64 + nn*16 + l15;
            s[nn][j] = (kcol <= qrow) ? s[nn][j]*0.125f : -1e30f;
          }
      } else {
#pragma unroll
        for (int nn = 0; nn < 4; ++nn)
#pragma unroll
          for (int j = 0; j < 4; ++j) s[nn][j] *= 0.125f;
      }

      // ---- online softmax (rows live across l15 lanes) ----
      float corr[4];
#pragma unroll
      for (int j = 0; j < 4; ++j) {
        float v = fmaxf(fmaxf(s[0][j], s[1][j]), fmaxf(s[2][j], s[3][j]));
        v = fmaxf(v, __shfl_xor(v, 1));
        v = fmaxf(v, __shfl_xor(v, 2));
        v = fmaxf(v, __shfl_xor(v, 4));
        v = fmaxf(v, __shfl_xor(v, 8));
        const float mn = fmaxf(mrow[j], v);
        corr[j] = __expf(mrow[j] - mn);
        mrow[j] = mn;
        float sum = 0.f;
#pragma unroll
        for (int nn = 0; nn < 4; ++nn) {
          const float p = __expf(s[nn][j] - mn);
          s[nn][j] = p;
          sum += p;
        }
        sum += __shfl_xor(sum, 1);
        sum += __shfl_xor(sum, 2);
        sum += __shfl_xor(sum, 4);
        sum += __shfl_xor(sum, 8);
        lrow[j] = lrow[j]*corr[j] + sum;
      }

#pragma unroll
      for (int d = 0; d < 4; ++d)
#pragma unroll
        for (int j = 0; j < 4; ++j) o[d][j] *= corr[j];

      // ---- P -> per-wave LDS (bf16), row-major [16 q][64 k], byte ^= ((row&7)<<4) ----
      const unsigned pbase = (unsigned)(w*2048);
#pragma unroll
      for (int nn = 0; nn < 4; ++nn)
#pragma unroll
        for (int j = 0; j < 4; ++j) {
          const unsigned r = (unsigned)(l4*4 + j);
          unsigned byte = r*128u + (unsigned)(nn*16 + l15)*2u;
          byte ^= ((r & 7u) << 4);
          *(unsigned short*)((char*)Pls + pbase + byte) = f2bf(s[nn][j]);
        }
      // same-wave cross-lane LDS handoff: order + completion, no workgroup barrier
      asm volatile("s_waitcnt lgkmcnt(0)" ::: "memory");

      // ---- PV ----
#pragma unroll
      for (int c = 0; c < 2; ++c) {
        unsigned abyte = (unsigned)(l15*128 + c*64 + l4*16);
        abyte ^= (((unsigned)l15 & 7u) << 4);
        const bf16x8 pa = *reinterpret_cast<const bf16x8*>((char*)Pls + pbase + abyte);
#pragma unroll
        for (int d = 0; d < 4; ++d) {
          const unsigned vbyte = (unsigned)((d*16 + l15)*128)
                               + (((unsigned)(c*64 + l4*16)) ^ (((unsigned)l15 & 7u) << 4));
          const bf16x8 vb = *reinterpret_cast<const bf16x8*>((const char*)Vs[cur] + vbyte);
          o[d] = __builtin_amdgcn_mfma_f32_16x16x32_bf16(pa, vb, o[d], 0, 0, 0);
        }
      }

      // drain this wave's LDS reads, then next-tile staging loads; one barrier per tile
      asm volatile("s_waitcnt lgkmcnt(0)" ::: "memory");
      asm volatile("s_waitcnt vmcnt(0)" ::: "memory");
      __builtin_amdgcn_s_barrier();
    }

#pragma unroll
    for (int d = 0; d < 4; ++d)
#pragma unroll
      for (int j = 0; j < 4; ++j) {
        const int row = qbase + w*16 + l4*4 + j;
        seqo[(size_t)(b*TT + row)*DD + h*64 + d*16 + l15] = o[d][j] / lrow[j];
      }
  }
}

// ---------------- exterior products + J6 map ----------------
__device__ __forceinline__ void ext6(const float* p, const float* q, float* L){
  L[0] = p[0]*q[1] - p[1]*q[0];
  L[1] = p[0]*q[2] - p[2]*q[0];
  L[2] = p[0]*q[3] - p[3]*q[0];
  L[3] = p[1]*q[2] - p[2]*q[1];
  L[4] = p[1]*q[3] - p[3]*q[1];
  L[5] = p[2]*q[3] - p[3]*q[2];
  const float n2 = L[0]*L[0]+L[1]*L[1]+L[2]*L[2]+L[3]*L[3]+L[4]*L[4]+L[5]*L[5];
  const float inv = 1.0f / fmaxf(sqrtf(n2), 1e-12f);
#pragma unroll
  for (int i = 0; i < 6; ++i) L[i] *= inv;
}

__global__ void exterior_kernel(const unsigned short* __restrict__ P,
                                float* __restrict__ Jw6, float* __restrict__ rd6)
{
  const int gid = blockIdx.x*256 + threadIdx.x;        // 65536 exact
  const int h = gid & 15, t = (gid >> 4) & (TT-1), b = gid >> 15;
  const size_t row = (size_t)(b*TT + t)*LDP;
  float w1[4], w2[4], r1[4], r2[4];
  if (t > 0) {
    const size_t rp = row - LDP;
#pragma unroll
    for (int j = 0; j < 4; ++j) w1[j] = bf2f(P[rp + 3072 + h*4 + j]);
  } else {
#pragma unroll
    for (int j = 0; j < 4; ++j) w1[j] = 0.f;
  }
#pragma unroll
  for (int j = 0; j < 4; ++j) {
    w2[j] = bf2f(P[row + 3136 + h*4 + j]);
    r1[j] = bf2f(P[row + 3200 + h*4 + j]);
    r2[j] = bf2f(P[row + 3264 + h*4 + j]);
  }
  float wl[6], rl[6];
  ext6(w1, w2, wl);
  ext6(r1, r2, rl);
  const float jw[6] = {wl[5], -wl[4], wl[3], wl[2], -wl[1], wl[0]};
  const size_t base = ((size_t)(b*HH + h)*TT + t)*6;
#pragma unroll
  for (int i = 0; i < 6; ++i) { Jw6[base+i] = jw[i]; rd6[base+i] = rl[i]; }
}

// ---------------- chunked scan: M[t+1] = d*(M[t] + Jw[t] (x) Jw[t]) ----------------
__global__ __launch_bounds__(64, 8)
void scan_passA(const float* __restrict__ Jw6, const float* __restrict__ decay_logits,
                float* __restrict__ E)
{
  const int bid = blockIdx.x;            // 512 = 32 seq * 16 chunks
  const int s = bid >> 4, c = bid & 15;
  const int lane = threadIdx.x;
  const int i = lane & 7, j = lane >> 3;
  const int ic = i < 6 ? i : 0, jc = j < 6 ? j : 0;
  const float d = sigmoidf_(decay_logits[s & (HH-1)]);
  const size_t base = ((size_t)s*TT + c*128)*6;
  float e = 0.f;
  for (int t = 0; t < 128; ++t) {
    const float ai = Jw6[base + t*6 + ic];
    const float aj = Jw6[base + t*6 + jc];
    e = d*(e + ai*aj);
  }
  if (i < 6 && j < 6) E[(size_t)bid*36 + j*6 + i] = e;
}

__global__ __launch_bounds__(64, 8)
void scan_passB(const float* __restrict__ E, const float* __restrict__ decay_logits,
                float* __restrict__ BC)
{
  const int s = blockIdx.x;              // 32
  const int lane = threadIdx.x;
  if (lane >= 36) return;
  const float d = sigmoidf_(decay_logits[s & (HH-1)]);
  const float dL = __powf(d, 128.0f);
  float bc = 0.f;
  for (int c = 0; c < 16; ++c) {
    BC[((size_t)s*16 + c)*36 + lane] = bc;
    bc = dL*bc + E[((size_t)s*16 + c)*36 + lane];
  }
}

__global__ __launch_bounds__(64, 8)
void scan_passC(const float* __restrict__ Jw6, const float* __restrict__ rd6,
                const float* __restrict__ BC, const float* __restrict__ decay_logits,
                const float* __restrict__ iter_mix, float* __restrict__ msc)
{
  const int bid = blockIdx.x;
  const int s = bid >> 4, c = bid & 15;
  const int h = s & (HH-1), bb = s >> 4;
  const int lane = threadIdx.x;
  const int i = lane & 7, j = lane >> 3;
  const bool valid = (i < 6) && (j < 6);
  const int ic = i < 6 ? i : 0, jc = j < 6 ? j : 0;
  const float d = sigmoidf_(decay_logits[h]);
  const float alpha = sigmoidf_(iter_mix[0]);
  float m = 0.f;
  if (valid) m = BC[((size_t)s*16 + c)*36 + j*6 + i];
  const size_t base = ((size_t)s*TT + c*128)*6;
  for (int t = 0; t < 128; ++t) {
    const float ai = Jw6[base + t*6 + ic];
    const float aj = Jw6[base + t*6 + jc];
    const float ri = rd6[base + t*6 + ic];
    const float rj = rd6[base + t*6 + jc];
    float part = valid ? ri*m : 0.f;            // y_j = sum_i r_i * M_ij
    part += __shfl_xor(part, 1);
    part += __shfl_xor(part, 2);
    part += __shfl_xor(part, 4);
    float contrib = (i == 0 && j < 6) ? part*((1.f-alpha)*rj + alpha*part) : 0.f;
    contrib += __shfl_xor(contrib, 8);
    contrib += __shfl_xor(contrib, 16);
    contrib += __shfl_xor(contrib, 32);
    if (lane == 0) msc[((size_t)bb*TT + c*128 + t)*HH + h] = contrib;
    m = d*(m + ai*aj);
  }
}

// ---------------- gate + mix -> z (bf16) ----------------
__global__ __launch_bounds__(256, 4)
void combine_kernel(const float* __restrict__ seqo, const unsigned short* __restrict__ P,
                    const float* __restrict__ msc, const float* __restrict__ mem_scale,
                    unsigned short* __restrict__ zb)
{
  const int w = threadIdx.x >> 6, lane = threadIdx.x & 63;
  const int row = blockIdx.x*4 + w;
  float val = 0.f;
  if (lane < HH) {
    const float ms = msc[(size_t)row*HH + lane];
    const float gl = bf2f(P[(size_t)row*LDP + 4352 + lane]);
    val = sigmoidf_(ms*mem_scale[lane]) * sigmoidf_(gl);
  }
  val += __shfl_xor(val, 1);
  val += __shfl_xor(val, 2);
  val += __shfl_xor(val, 4);
  val += __shfl_xor(val, 8);
  const float g = __shfl(val, 0) * (1.0f/16.0f);
  for (int it = 0; it < 16; ++it) {
    const int dcol = it*64 + lane;
    const float z = seqo[(size_t)row*DD + dcol] + g*bf2f(P[(size_t)row*LDP + 3328 + dcol]);
    zb[(size_t)row*DD + dcol] = f2bf(z);
  }
}

// ---------------- launch ----------------
extern "C" void kernel_launch(void* const* d_in, const int* in_sizes, int n_in,
                              void* d_out, int out_size, void* d_ws, size_t ws_size,
                              hipStream_t stream)
{
  const float* x            = (const float*)d_in[0];
  const float* qkv_w        = (const float*)d_in[1];
  const float* qkv_b        = (const float*)d_in[2];
  const float* w1w          = (const float*)d_in[3];
  const float* w2w          = (const float*)d_in[4];
  const float* r1w          = (const float*)d_in[5];
  const float* r2w          = (const float*)d_in[6];
  const float* memv_w       = (const float*)d_in[7];
  const float* memv_b       = (const float*)d_in[8];
  const float* memg_w       = (const float*)d_in[9];
  const float* memg_b       = (const float*)d_in[10];
  const float* mem_scale    = (const float*)d_in[11];
  const float* iter_mix     = (const float*)d_in[12];
  const float* out_w        = (const float*)d_in[13];
  const float* out_b        = (const float*)d_in[14];
  const float* decay_logits = (const float*)d_in[15];

  char* ws = (char*)d_ws;
  unsigned short* xb   = (unsigned short*)(ws + 0);          //  8,388,608 B
  unsigned short* Wcat = (unsigned short*)(ws + 8388608);    // 11,042,816 B
  float*          bcat = (float*)         (ws + 19431424);   //     17,472 B
  unsigned short* P    = (unsigned short*)(ws + 19449088);   // 35,782,656 B
  unsigned short* VT   = (unsigned short*)(ws + 55231744);   //  8,388,608 B
  float*          seqo = (float*)         (ws + 63620352);   // 16,777,216 B
  float*          Jw6  = (float*)         (ws + 80397568);   //  1,572,864 B
  float*          rd6  = (float*)         (ws + 81970432);   //  1,572,864 B
  float*          E    = (float*)         (ws + 83543296);   //     73,728 B
  float*          BC   = (float*)         (ws + 83617024);   //     73,728 B
  float*          msc  = (float*)         (ws + 83690752);   //    262,144 B
  unsigned short* zb   = xb;  // xb dead after GEMM1; reuse for z

  prep_weights_kernel<<<5392, 256, 0, stream>>>(qkv_w, w1w, w2w, r1w, r2w, memv_w, memg_w, out_w,
                                                qkv_b, memv_b, memg_b, Wcat, bcat);
  convert_x_kernel<<<4096, 256, 0, stream>>>(x, xb);
  gemm_bt_kernel<false><<<dim3(32, 35), 256, 0, stream>>>(xb, 1024, Wcat, 1024, bcat,
                                                          P, LDP, 4368, 1024);
  transpose_v_kernel<<<dim3(32, 16, 2), 256, 0, stream>>>(P, VT);
  attn_kernel<<<512, 256, 0, stream>>>(P, VT, seqo);
  exterior_kernel<<<256, 256, 0, stream>>>(P, Jw6, rd6);
  scan_passA<<<512, 64, 0, stream>>>(Jw6, decay_logits, E);
  scan_passB<<<32, 64, 0, stream>>>(E, decay_logits, BC);
  scan_passC<<<512, 64, 0, stream>>>(Jw6, rd6, BC, decay_logits, iter_mix, msc);
  combine_kernel<<<1024, 256, 0, stream>>>(seqo, P, msc, mem_scale, zb);
  gemm_bt_kernel<true><<<dim3(32, 8), 256, 0, stream>>>(zb, 1024, Wcat + (size_t)4368*1024, 1024,
                                                        out_b, d_out, 1024, 1024, 1024);
}

// Round 6
// 226.339 us; speedup vs baseline: 1.1225x; 1.0823x over previous
//
#include <hip/hip_runtime.h>
#include <stdint.h>

#define TT 2048
#define DD 1024
#define HH 16
#define LDP 4368   // concat width: 3072 qkv | 64 w1 | 64 w2 | 64 r1 | 64 r2 | 1024 memv | 16 gate

using bf16x8 = __attribute__((ext_vector_type(8))) __bf16;
using f32x4  = __attribute__((ext_vector_type(4))) float;

__device__ __forceinline__ float bf2f(unsigned short u){
  unsigned int x = ((unsigned int)u) << 16;
  return __builtin_bit_cast(float, x);
}
__device__ __forceinline__ unsigned short f2bf(float f){
  unsigned int x = __builtin_bit_cast(unsigned int, f);
  x += 0x7fffu + ((x >> 16) & 1u);
  return (unsigned short)(x >> 16);
}
__device__ __forceinline__ float sigmoidf_(float x){ return 1.0f/(1.0f+__expf(-x)); }

// global -> LDS direct (16B/lane). LDS base must be wave-uniform; HW adds lane*16.
__device__ __forceinline__ void gload_lds16(const void* g, void* l){
  auto gp = (const __attribute__((address_space(1))) unsigned int*)(uintptr_t)g;
  auto lp = (__attribute__((address_space(3))) unsigned int*)(unsigned int)(uintptr_t)l;
  __builtin_amdgcn_global_load_lds(gp, lp, 16, 0, 0);
}

// ---------------- weight prep ----------------
__global__ void prep_weights_kernel(const float* __restrict__ qkv_w, const float* __restrict__ w1w,
                                    const float* __restrict__ w2w, const float* __restrict__ r1w,
                                    const float* __restrict__ r2w, const float* __restrict__ memv_w,
                                    const float* __restrict__ memg_w, const float* __restrict__ out_w,
                                    const float* __restrict__ qkv_b, const float* __restrict__ memv_b,
                                    const float* __restrict__ memg_b,
                                    unsigned short* __restrict__ Wcat, float* __restrict__ bcat)
{
  const int idx = blockIdx.x*256 + threadIdx.x;     // 5392*256 exact
  {
    const int row = idx >> 8, c4 = (idx & 255)*4;
    const float* src; int r;
    if      (row < 3072) { src = qkv_w;  r = row; }
    else if (row < 3136) { src = w1w;    r = row-3072; }
    else if (row < 3200) { src = w2w;    r = row-3136; }
    else if (row < 3264) { src = r1w;    r = row-3200; }
    else if (row < 3328) { src = r2w;    r = row-3264; }
    else if (row < 4352) { src = memv_w; r = row-3328; }
    else if (row < 4368) { src = memg_w; r = row-4352; }
    else                 { src = out_w;  r = row-4368; }
    const float4 v = *(const float4*)(src + (size_t)r*1024 + c4);
    ushort4 o; o.x=f2bf(v.x); o.y=f2bf(v.y); o.z=f2bf(v.z); o.w=f2bf(v.w);
    *(ushort4*)(Wcat + (size_t)row*1024 + c4) = o;
  }
  if (idx < 4368) {
    float v;
    if      (idx < 3072) v = qkv_b[idx];
    else if (idx < 3328) v = 0.f;
    else if (idx < 4352) v = memv_b[idx-3328];
    else                 v = memg_b[idx-4352];
    bcat[idx] = v;
  }
}

__global__ void convert_x_kernel(const float* __restrict__ x, unsigned short* __restrict__ xb)
{
  const int idx = blockIdx.x*256 + threadIdx.x;   // 4096*256 exact, 4 elems each
  const float4 v = ((const float4*)x)[idx];
  ushort4 o; o.x=f2bf(v.x); o.y=f2bf(v.y); o.z=f2bf(v.z); o.w=f2bf(v.w);
  ((ushort4*)xb)[idx] = o;
}

// ---------------- GEMM: C[M,N] = A[M,K] * Bt[N,K]^T + bias ----------------
// 2-phase pipeline: stage(next) issued before compute(cur); one vmcnt(0)+barrier per k-step.
// (verbatim the round-4-passing version)
template<bool OUTF32>
__global__ __launch_bounds__(256, 2)
void gemm_bt_kernel(const unsigned short* __restrict__ A, int lda,
                    const unsigned short* __restrict__ Bt, int ldb,
                    const float* __restrict__ bias,
                    void* __restrict__ Cout, int ldc, int N, int K)
{
  __shared__ unsigned short As[2][128*32];
  __shared__ unsigned short Bs[2][128*32];
  const int tid = threadIdx.x;
  const int w = tid >> 6, lane = tid & 63;
  const int l15 = lane & 15, l4 = lane >> 4;
  const int m0 = blockIdx.x * 128;
  const int n0 = blockIdx.y * 128;
  const int wr = (w >> 1) * 64, wc = (w & 1) * 64;

  const f32x4 zero = {0.f,0.f,0.f,0.f};
  f32x4 acc[4][4];
#pragma unroll
  for (int i = 0; i < 4; ++i)
#pragma unroll
    for (int j = 0; j < 4; ++j) acc[i][j] = zero;

  const int srow = lane >> 2;
  const int k8   = (lane & 3) * 8;

  auto stage = [&](int k0, int buf) {
#pragma unroll
    for (int q = 0; q < 4; ++q) {
      const int c = q*4 + w;                 // 0..15 chunk of 1KB
      const int rloc = (c & 7)*16 + srow;
      if (c < 8) {
        gload_lds16(A + (size_t)(m0 + rloc)*lda + k0 + k8, (char*)As[buf] + (c&7)*1024);
      } else {
        int nrow = n0 + rloc; if (nrow >= N) nrow = N - 1;
        gload_lds16(Bt + (size_t)nrow*ldb + k0 + k8, (char*)Bs[buf] + (c&7)*1024);
      }
    }
  };

  stage(0, 0);
  asm volatile("s_waitcnt vmcnt(0)" ::: "memory");
  __builtin_amdgcn_s_barrier();

  for (int k0 = 0; k0 < K; k0 += 32) {
    const int cur = (k0 >> 5) & 1;
    if (k0 + 32 < K) stage(k0 + 32, cur ^ 1);   // next-tile loads fly under compute

    bf16x8 af[4], bfr[4];
#pragma unroll
    for (int i = 0; i < 4; ++i) {
      af[i]  = *reinterpret_cast<const bf16x8*>(&As[cur][(wr + i*16 + l15)*32 + l4*8]);
      bfr[i] = *reinterpret_cast<const bf16x8*>(&Bs[cur][(wc + i*16 + l15)*32 + l4*8]);
    }
#pragma unroll
    for (int i = 0; i < 4; ++i)
#pragma unroll
      for (int j = 0; j < 4; ++j)
        acc[i][j] = __builtin_amdgcn_mfma_f32_16x16x32_bf16(af[i], bfr[j], acc[i][j], 0, 0, 0);

    asm volatile("s_waitcnt vmcnt(0)" ::: "memory");
    __builtin_amdgcn_s_barrier();
  }

#pragma unroll
  for (int i = 0; i < 4; ++i) {
    const int rowb = m0 + wr + i*16 + l4*4;
#pragma unroll
    for (int j = 0; j < 4; ++j) {
      const int col = n0 + wc + j*16 + l15;
      if (col < N) {
        const float bv = bias ? bias[col] : 0.0f;
#pragma unroll
        for (int r = 0; r < 4; ++r) {
          const float v = acc[i][j][r] + bv;
          const size_t off = (size_t)(rowb + r)*ldc + col;
          if (OUTF32) ((float*)Cout)[off] = v;
          else        ((unsigned short*)Cout)[off] = f2bf(v);
        }
      }
    }
  }
}

// ---------------- V transpose: P v-cols -> VT[b][h][d][t] ----------------
__global__ __launch_bounds__(256, 4)
void transpose_v_kernel(const unsigned short* __restrict__ P, unsigned short* __restrict__ VT)
{
  __shared__ unsigned short tile[64][66];
  const int t0 = blockIdx.x*64, h = blockIdx.y, b = blockIdx.z;
  for (int i = threadIdx.x; i < 4096; i += 256) {
    const int r = i >> 6, c = i & 63;
    tile[r][c] = P[(size_t)(b*TT + t0 + r)*LDP + 2048 + h*64 + c];
  }
  __syncthreads();
  for (int i = threadIdx.x; i < 4096; i += 256) {
    const int d = i >> 6, tl = i & 63;
    VT[(size_t)((b*HH + h)*64 + d)*TT + t0 + tl] = tile[tl][d];
  }
}

// ---------------- flash attention (paired q-tiles, swapped-QK lane-local softmax) ----------------
// 512 blocks (dim3(16,16,2)), pairs {pi, 31-pi}: 33 k-tile iterations per block, uniform.
// Swapped QK^T: mfma(K,Q) -> S^T; lane's q-row = w*16 + l15, 16 k-values in regs.
__global__ __launch_bounds__(256, 2)
void attn_kernel(const unsigned short* __restrict__ P,
                 const unsigned short* __restrict__ VT,
                 float* __restrict__ seqo)
{
  __shared__ unsigned short Ks[2][64*64];  // [k-row][64 d], rows XOR-swizzled
  __shared__ unsigned short Vs[2][64*64];  // [d-row][64 k], rows XOR-swizzled
  __shared__ unsigned short Pls[4*16*64];  // per-wave 16x64 [q][k], XOR-swizzled

  const int tid = threadIdx.x;
  const int w = tid >> 6, lane = tid & 63;
  const int l15 = lane & 15, l4 = lane >> 4;
  const int pi = blockIdx.x, h = blockIdx.y, b = blockIdx.z;

  auto stage = [&](int kt, int bufsel) {
#pragma unroll
    for (int q2 = 0; q2 < 2; ++q2) {
      const int idx = q2*256 + tid;
      const int r = idx >> 3;
      const int cb = ((idx & 7)*16) ^ ((r & 7) << 4);   // swizzled source column byte
      gload_lds16(P + (size_t)(b*TT + kt*64 + r)*LDP + 1024 + h*64 + (cb >> 1),
                  (char*)Ks[bufsel] + q2*4096 + w*1024);
      gload_lds16(VT + (size_t)((b*HH + h)*64 + r)*TT + kt*64 + (cb >> 1),
                  (char*)Vs[bufsel] + q2*4096 + w*1024);
    }
  };

  const f32x4 zero = {0.f,0.f,0.f,0.f};
  const unsigned xorb = ((unsigned)(l15 & 7u)) << 4;

  for (int rep = 0; rep < 2; ++rep) {
    const int qt = rep == 0 ? pi : 31 - pi;
    const int qbase = qt * 64;
    const int qrow = qbase + w*16 + l15;   // this lane's q-row

    bf16x8 qa[2];
    {
      const size_t base = (size_t)(b*TT + qbase + w*16 + l15)*LDP + h*64 + l4*8;
      qa[0] = *reinterpret_cast<const bf16x8*>(P + base);
      qa[1] = *reinterpret_cast<const bf16x8*>(P + base + 32);
    }

    f32x4 o[4];
#pragma unroll
    for (int d = 0; d < 4; ++d) o[d] = zero;
    float mrow = -1e30f;
    float lrow = 0.f;

    stage(0, 0);
    asm volatile("s_waitcnt vmcnt(0)" ::: "memory");
    __builtin_amdgcn_s_barrier();

    for (int kt = 0; kt <= qt; ++kt) {
      const int cur = kt & 1;
      if (kt < qt) stage(kt + 1, cur ^ 1);   // loads fly under this iteration's compute

      // ---- QK^T swapped: s[nn] = S^T tile, lane holds k = nn*16 + l4*4 + j for q = qrow ----
      f32x4 s[4];
#pragma unroll
      for (int nn = 0; nn < 4; ++nn) {
        f32x4 a = zero;
#pragma unroll
        for (int c = 0; c < 2; ++c) {
          const unsigned kbyte = (unsigned)((nn*16 + l15)*128)
                               + (((unsigned)(c*64 + l4*16)) ^ xorb);
          const bf16x8 kb = *reinterpret_cast<const bf16x8*>((const char*)Ks[cur] + kbyte);
          a = __builtin_amdgcn_mfma_f32_16x16x32_bf16(kb, qa[c], a, 0, 0, 0);
        }
        s[nn] = a;
      }

      if (kt == qt) {
#pragma unroll
        for (int nn = 0; nn < 4; ++nn)
#pragma unroll
          for (int j = 0; j < 4; ++j) {
            const int kcol = kt*64 + nn*16 + l4*4 + j;
            s[nn][j] = (kcol <= qrow) ? s[nn][j]*0.125f : -1e30f;
          }
      } else {
#pragma unroll
        for (int nn = 0; nn < 4; ++nn)
#pragma unroll
          for (int j = 0; j < 4; ++j) s[nn][j] *= 0.125f;
      }

      // ---- online softmax, lane-local row (row spread over 4 lanes: xor16/xor32) ----
      float a0 = fmaxf(fmaxf(s[0][0], s[0][1]), fmaxf(s[0][2], s[0][3]));
      float a1 = fmaxf(fmaxf(s[1][0], s[1][1]), fmaxf(s[1][2], s[1][3]));
      float a2 = fmaxf(fmaxf(s[2][0], s[2][1]), fmaxf(s[2][2], s[2][3]));
      float a3 = fmaxf(fmaxf(s[3][0], s[3][1]), fmaxf(s[3][2], s[3][3]));
      float tmax = fmaxf(fmaxf(a0, a1), fmaxf(a2, a3));
      tmax = fmaxf(tmax, __shfl_xor(tmax, 16));
      tmax = fmaxf(tmax, __shfl_xor(tmax, 32));
      const float mn = fmaxf(mrow, tmax);
      const float corr = __expf(mrow - mn);
      mrow = mn;
      float lsum = 0.f;
#pragma unroll
      for (int nn = 0; nn < 4; ++nn) {
        float p0 = __expf(s[nn][0] - mn);
        float p1 = __expf(s[nn][1] - mn);
        float p2 = __expf(s[nn][2] - mn);
        float p3 = __expf(s[nn][3] - mn);
        s[nn][0] = p0; s[nn][1] = p1; s[nn][2] = p2; s[nn][3] = p3;
        lsum += (p0 + p1) + (p2 + p3);
      }
      lsum += __shfl_xor(lsum, 16);
      lsum += __shfl_xor(lsum, 32);
      lrow = lrow*corr + lsum;

      // o's q-index is l4*4+j: fetch corr for that q from the lane holding it (width-16 group)
      float corrq[4];
#pragma unroll
      for (int j = 0; j < 4; ++j) corrq[j] = __shfl(corr, l4*4 + j, 16);
#pragma unroll
      for (int d = 0; d < 4; ++d)
#pragma unroll
        for (int j = 0; j < 4; ++j) o[d][j] *= corrq[j];

      // ---- P^T regs -> Pls [q=l15][k], packed pairs, XOR-swizzled (row = l15) ----
      const unsigned pbase = (unsigned)(w*2048);
#pragma unroll
      for (int nn = 0; nn < 4; ++nn)
#pragma unroll
        for (int jp = 0; jp < 2; ++jp) {
          const unsigned v = (unsigned)f2bf(s[nn][jp*2]) | ((unsigned)f2bf(s[nn][jp*2+1]) << 16);
          const unsigned k = (unsigned)(nn*16 + l4*4 + jp*2);
          unsigned byte = (unsigned)l15*128u + k*2u;
          byte ^= xorb;
          *(unsigned*)((char*)Pls + pbase + byte) = v;
        }
      // same-wave cross-lane LDS handoff: order + completion, no workgroup barrier
      asm volatile("s_waitcnt lgkmcnt(0)" ::: "memory");

      // ---- PV ----
#pragma unroll
      for (int c = 0; c < 2; ++c) {
        unsigned abyte = (unsigned)(l15*128) + (((unsigned)(c*64 + l4*16)) ^ xorb);
        const bf16x8 pa = *reinterpret_cast<const bf16x8*>((char*)Pls + pbase + abyte);
#pragma unroll
        for (int d = 0; d < 4; ++d) {
          const unsigned vbyte = (unsigned)((d*16 + l15)*128)
                               + (((unsigned)(c*64 + l4*16)) ^ xorb);
          const bf16x8 vb = *reinterpret_cast<const bf16x8*>((const char*)Vs[cur] + vbyte);
          o[d] = __builtin_amdgcn_mfma_f32_16x16x32_bf16(pa, vb, o[d], 0, 0, 0);
        }
      }

      // drain this wave's LDS reads, then next-tile staging loads; one barrier per tile
      asm volatile("s_waitcnt lgkmcnt(0)" ::: "memory");
      asm volatile("s_waitcnt vmcnt(0)" ::: "memory");
      __builtin_amdgcn_s_barrier();
    }

    float lrowq[4];
#pragma unroll
    for (int j = 0; j < 4; ++j) lrowq[j] = __shfl(lrow, l4*4 + j, 16);
#pragma unroll
    for (int d = 0; d < 4; ++d)
#pragma unroll
      for (int j = 0; j < 4; ++j) {
        const int row = qbase + w*16 + l4*4 + j;
        seqo[(size_t)(b*TT + row)*DD + h*64 + d*16 + l15] = o[d][j] / lrowq[j];
      }
  }
}

// ---------------- exterior products + J6 map ----------------
__device__ __forceinline__ void ext6(const float* p, const float* q, float* L){
  L[0] = p[0]*q[1] - p[1]*q[0];
  L[1] = p[0]*q[2] - p[2]*q[0];
  L[2] = p[0]*q[3] - p[3]*q[0];
  L[3] = p[1]*q[2] - p[2]*q[1];
  L[4] = p[1]*q[3] - p[3]*q[1];
  L[5] = p[2]*q[3] - p[3]*q[2];
  const float n2 = L[0]*L[0]+L[1]*L[1]+L[2]*L[2]+L[3]*L[3]+L[4]*L[4]+L[5]*L[5];
  const float inv = 1.0f / fmaxf(sqrtf(n2), 1e-12f);
#pragma unroll
  for (int i = 0; i < 6; ++i) L[i] *= inv;
}

__global__ void exterior_kernel(const unsigned short* __restrict__ P,
                                float* __restrict__ Jw6, float* __restrict__ rd6)
{
  const int gid = blockIdx.x*256 + threadIdx.x;        // 65536 exact
  const int h = gid & 15, t = (gid >> 4) & (TT-1), b = gid >> 15;
  const size_t row = (size_t)(b*TT + t)*LDP;
  float w1[4], w2[4], r1[4], r2[4];
  if (t > 0) {
    const size_t rp = row - LDP;
#pragma unroll
    for (int j = 0; j < 4; ++j) w1[j] = bf2f(P[rp + 3072 + h*4 + j]);
  } else {
#pragma unroll
    for (int j = 0; j < 4; ++j) w1[j] = 0.f;
  }
#pragma unroll
  for (int j = 0; j < 4; ++j) {
    w2[j] = bf2f(P[row + 3136 + h*4 + j]);
    r1[j] = bf2f(P[row + 3200 + h*4 + j]);
    r2[j] = bf2f(P[row + 3264 + h*4 + j]);
  }
  float wl[6], rl[6];
  ext6(w1, w2, wl);
  ext6(r1, r2, rl);
  const float jw[6] = {wl[5], -wl[4], wl[3], wl[2], -wl[1], wl[0]};
  const size_t base = ((size_t)(b*HH + h)*TT + t)*6;
#pragma unroll
  for (int i = 0; i < 6; ++i) { Jw6[base+i] = jw[i]; rd6[base+i] = rl[i]; }
}

// ---------------- chunked scan: M[t+1] = d*(M[t] + Jw[t] (x) Jw[t]) ----------------
__global__ __launch_bounds__(64, 8)
void scan_passA(const float* __restrict__ Jw6, const float* __restrict__ decay_logits,
                float* __restrict__ E)
{
  const int bid = blockIdx.x;            // 512 = 32 seq * 16 chunks
  const int s = bid >> 4, c = bid & 15;
  const int lane = threadIdx.x;
  const int i = lane & 7, j = lane >> 3;
  const int ic = i < 6 ? i : 0, jc = j < 6 ? j : 0;
  const float d = sigmoidf_(decay_logits[s & (HH-1)]);
  const size_t base = ((size_t)s*TT + c*128)*6;
  float e = 0.f;
  for (int t = 0; t < 128; ++t) {
    const float ai = Jw6[base + t*6 + ic];
    const float aj = Jw6[base + t*6 + jc];
    e = d*(e + ai*aj);
  }
  if (i < 6 && j < 6) E[(size_t)bid*36 + j*6 + i] = e;
}

__global__ __launch_bounds__(64, 8)
void scan_passB(const float* __restrict__ E, const float* __restrict__ decay_logits,
                float* __restrict__ BC)
{
  const int s = blockIdx.x;              // 32
  const int lane = threadIdx.x;
  if (lane >= 36) return;
  const float d = sigmoidf_(decay_logits[s & (HH-1)]);
  const float dL = __powf(d, 128.0f);
  float bc = 0.f;
  for (int c = 0; c < 16; ++c) {
    BC[((size_t)s*16 + c)*36 + lane] = bc;
    bc = dL*bc + E[((size_t)s*16 + c)*36 + lane];
  }
}

__global__ __launch_bounds__(64, 8)
void scan_passC(const float* __restrict__ Jw6, const float* __restrict__ rd6,
                const float* __restrict__ BC, const float* __restrict__ decay_logits,
                const float* __restrict__ iter_mix, float* __restrict__ msc)
{
  const int bid = blockIdx.x;
  const int s = bid >> 4, c = bid & 15;
  const int h = s & (HH-1), bb = s >> 4;
  const int lane = threadIdx.x;
  const int i = lane & 7, j = lane >> 3;
  const bool valid = (i < 6) && (j < 6);
  const int ic = i < 6 ? i : 0, jc = j < 6 ? j : 0;
  const float d = sigmoidf_(decay_logits[h]);
  const float alpha = sigmoidf_(iter_mix[0]);
  float m = 0.f;
  if (valid) m = BC[((size_t)s*16 + c)*36 + j*6 + i];
  const size_t base = ((size_t)s*TT + c*128)*6;
  for (int t = 0; t < 128; ++t) {
    const float ai = Jw6[base + t*6 + ic];
    const float aj = Jw6[base + t*6 + jc];
    const float ri = rd6[base + t*6 + ic];
    const float rj = rd6[base + t*6 + jc];
    float part = valid ? ri*m : 0.f;            // y_j = sum_i r_i * M_ij
    part += __shfl_xor(part, 1);
    part += __shfl_xor(part, 2);
    part += __shfl_xor(part, 4);
    float contrib = (i == 0 && j < 6) ? part*((1.f-alpha)*rj + alpha*part) : 0.f;
    contrib += __shfl_xor(contrib, 8);
    contrib += __shfl_xor(contrib, 16);
    contrib += __shfl_xor(contrib, 32);
    if (lane == 0) msc[((size_t)bb*TT + c*128 + t)*HH + h] = contrib;
    m = d*(m + ai*aj);
  }
}

// ---------------- gate + mix -> z (bf16) ----------------
__global__ __launch_bounds__(256, 4)
void combine_kernel(const float* __restrict__ seqo, const unsigned short* __restrict__ P,
                    const float* __restrict__ msc, const float* __restrict__ mem_scale,
                    unsigned short* __restrict__ zb)
{
  const int w = threadIdx.x >> 6, lane = threadIdx.x & 63;
  const int row = blockIdx.x*4 + w;
  float val = 0.f;
  if (lane < HH) {
    const float ms = msc[(size_t)row*HH + lane];
    const float gl = bf2f(P[(size_t)row*LDP + 4352 + lane]);
    val = sigmoidf_(ms*mem_scale[lane]) * sigmoidf_(gl);
  }
  val += __shfl_xor(val, 1);
  val += __shfl_xor(val, 2);
  val += __shfl_xor(val, 4);
  val += __shfl_xor(val, 8);
  const float g = __shfl(val, 0) * (1.0f/16.0f);
  for (int it = 0; it < 16; ++it) {
    const int dcol = it*64 + lane;
    const float z = seqo[(size_t)row*DD + dcol] + g*bf2f(P[(size_t)row*LDP + 3328 + dcol]);
    zb[(size_t)row*DD + dcol] = f2bf(z);
  }
}

// ---------------- launch ----------------
extern "C" void kernel_launch(void* const* d_in, const int* in_sizes, int n_in,
                              void* d_out, int out_size, void* d_ws, size_t ws_size,
                              hipStream_t stream)
{
  const float* x            = (const float*)d_in[0];
  const float* qkv_w        = (const float*)d_in[1];
  const float* qkv_b        = (const float*)d_in[2];
  const float* w1w          = (const float*)d_in[3];
  const float* w2w          = (const float*)d_in[4];
  const float* r1w          = (const float*)d_in[5];
  const float* r2w          = (const float*)d_in[6];
  const float* memv_w       = (const float*)d_in[7];
  const float* memv_b       = (const float*)d_in[8];
  const float* memg_w       = (const float*)d_in[9];
  const float* memg_b       = (const float*)d_in[10];
  const float* mem_scale    = (const float*)d_in[11];
  const float* iter_mix     = (const float*)d_in[12];
  const float* out_w        = (const float*)d_in[13];
  const float* out_b        = (const float*)d_in[14];
  const float* decay_logits = (const float*)d_in[15];

  char* ws = (char*)d_ws;
  unsigned short* xb   = (unsigned short*)(ws + 0);          //  8,388,608 B
  unsigned short* Wcat = (unsigned short*)(ws + 8388608);    // 11,042,816 B
  float*          bcat = (float*)         (ws + 19431424);   //     17,472 B
  unsigned short* P    = (unsigned short*)(ws + 19449088);   // 35,782,656 B
  unsigned short* VT   = (unsigned short*)(ws + 55231744);   //  8,388,608 B
  float*          seqo = (float*)         (ws + 63620352);   // 16,777,216 B
  float*          Jw6  = (float*)         (ws + 80397568);   //  1,572,864 B
  float*          rd6  = (float*)         (ws + 81970432);   //  1,572,864 B
  float*          E    = (float*)         (ws + 83543296);   //     73,728 B
  float*          BC   = (float*)         (ws + 83617024);   //     73,728 B
  float*          msc  = (float*)         (ws + 83690752);   //    262,144 B
  unsigned short* zb   = xb;  // xb dead after GEMM1; reuse for z

  prep_weights_kernel<<<5392, 256, 0, stream>>>(qkv_w, w1w, w2w, r1w, r2w, memv_w, memg_w, out_w,
                                                qkv_b, memv_b, memg_b, Wcat, bcat);
  convert_x_kernel<<<4096, 256, 0, stream>>>(x, xb);
  gemm_bt_kernel<false><<<dim3(32, 35), 256, 0, stream>>>(xb, 1024, Wcat, 1024, bcat,
                                                          P, LDP, 4368, 1024);
  transpose_v_kernel<<<dim3(32, 16, 2), 256, 0, stream>>>(P, VT);
  attn_kernel<<<dim3(16, 16, 2), 256, 0, stream>>>(P, VT, seqo);
  exterior_kernel<<<256, 256, 0, stream>>>(P, Jw6, rd6);
  scan_passA<<<512, 64, 0, stream>>>(Jw6, decay_logits, E);
  scan_passB<<<32, 64, 0, stream>>>(E, decay_logits, BC);
  scan_passC<<<512, 64, 0, stream>>>(Jw6, rd6, BC, decay_logits, iter_mix, msc);
  combine_kernel<<<1024, 256, 0, stream>>>(seqo, P, msc, mem_scale, zb);
  gemm_bt_kernel<true><<<dim3(32, 8), 256, 0, stream>>>(zb, 1024, Wcat + (size_t)4368*1024, 1024,
                                                        out_b, d_out, 1024, 1024, 1024);
}